// Round 8
// baseline (6931.454 us; speedup 1.0000x reference)
//
#include <hip/hip_runtime.h>

#define B_  64
#define T_  512
#define I_  256
#define H_  512
#define O_  256
#define SENT 0x7F7F7F7Fu
#define SLOT_BYTES 16384         // 32 rows x 256 cols bf16 (groups A:0-15, B:16-31)
#define BLK_SLOT_ELEMS 32768     // 4 slots per block, in ushorts (64 KB)

typedef __attribute__((ext_vector_type(8))) __bf16 bf16x8;
typedef __attribute__((ext_vector_type(4))) float f32x4;
typedef unsigned int u32x4 __attribute__((ext_vector_type(4)));

__device__ __forceinline__ unsigned short f2bf(float f) {
    unsigned int u = __float_as_uint(f);
    unsigned int r = (u + 0x7fffu + ((u >> 16) & 1u)) >> 16;
    return (unsigned short)r;
}

__device__ __forceinline__ float tanh_fast(float x) {
    float e = __expf(2.0f * x);
    float d = e + 1.0f;
    float r;
    asm("v_rcp_f32 %0, %1" : "=v"(r) : "v"(d));
    return 1.0f - 2.0f * r;
}

// ---------------- convert f32 -> bf16 ----------------
__global__ void cvt_kernel(const float* __restrict__ in, unsigned short* __restrict__ out, int n4) {
    int i = blockIdx.x * blockDim.x + threadIdx.x;
    if (i >= n4) return;
    float4 f = reinterpret_cast<const float4*>(in)[i];
    ushort4 o;
    o.x = f2bf(f.x); o.y = f2bf(f.y); o.z = f2bf(f.z); o.w = f2bf(f.w);
    reinterpret_cast<ushort4*>(out)[i] = o;
}

// ---------------- generic GEMM: C = A @ Bw^T + b0 + b1 ----------------
// perm!=0: store C with column permutation col' = (col&15)*32 + (col>>4)
// (N must be 512) so the recurrence can read xp as contiguous dwordx4.
__global__ __launch_bounds__(256) void gemm_kernel(
    const unsigned short* __restrict__ A,
    const unsigned short* __restrict__ Bw,
    const float* __restrict__ b0,
    const float* __restrict__ b1,
    float* __restrict__ C,
    int M, int N, int K, int perm)
{
    const int m0 = blockIdx.x * 64;
    const int n0 = blockIdx.y * 64;
    const int tid = threadIdx.x;
    const int wv = tid >> 6;
    const int l = tid & 63;
    const int lr = l & 15;
    const int lk = (l >> 4) * 8;
    const int arow = m0 + wv * 16 + lr;

    f32x4 acc[4] = {{0,0,0,0},{0,0,0,0},{0,0,0,0},{0,0,0,0}};
    const int nks = K / 32;
    for (int ks = 0; ks < nks; ++ks) {
        bf16x8 a = *reinterpret_cast<const bf16x8*>(A + (size_t)arow * K + ks * 32 + lk);
        #pragma unroll
        for (int nt = 0; nt < 4; ++nt) {
            bf16x8 b = *reinterpret_cast<const bf16x8*>(Bw + (size_t)(n0 + nt * 16 + lr) * K + ks * 32 + lk);
            acc[nt] = __builtin_amdgcn_mfma_f32_16x16x32_bf16(a, b, acc[nt], 0, 0, 0);
        }
    }
    #pragma unroll
    for (int nt = 0; nt < 4; ++nt) {
        #pragma unroll
        for (int r = 0; r < 4; ++r) {
            int row = m0 + wv * 16 + (l >> 4) * 4 + r;
            int col = n0 + nt * 16 + lr;
            float v = acc[nt][r];
            if (b0) v += b0[col];
            if (b1) v += b1[col];
            int cs = perm ? ((col & 15) * 32 + (col >> 4)) : col;
            C[(size_t)row * N + cs] = v;
        }
    }
}

// ---------------- recurrence (sentinel protocol, 2 batch groups per block) ----------------
#define LDW8(ARR, BASE) \
    asm volatile( \
        "global_load_dwordx4 %0, %8, %9 offset:0\n\t" \
        "global_load_dwordx4 %1, %8, %9 offset:64\n\t" \
        "global_load_dwordx4 %2, %8, %9 offset:128\n\t" \
        "global_load_dwordx4 %3, %8, %9 offset:192\n\t" \
        "global_load_dwordx4 %4, %8, %9 offset:256\n\t" \
        "global_load_dwordx4 %5, %8, %9 offset:320\n\t" \
        "global_load_dwordx4 %6, %8, %9 offset:384\n\t" \
        "global_load_dwordx4 %7, %8, %9 offset:448\n\t" \
        "s_waitcnt vmcnt(0)" \
        : "=&v"(ARR[0]), "=&v"(ARR[1]), "=&v"(ARR[2]), "=&v"(ARR[3]), \
          "=&v"(ARR[4]), "=&v"(ARR[5]), "=&v"(ARR[6]), "=&v"(ARR[7]) \
        : "v"(BASE), "s"(w))

// per-group main-loop bundle: 4 xp dwordx4 (HBM, permuted layout) + 8 peer-h dwordx4 (MALL)
#define LOAD_XP_PEER(XPQ, AFP, VSLR, XPBASE, SLBASE) \
    asm volatile( \
        "global_load_dwordx4 %0, %12, %16\n\t" \
        "global_load_dwordx4 %1, %13, %16\n\t" \
        "global_load_dwordx4 %2, %14, %16\n\t" \
        "global_load_dwordx4 %3, %15, %16\n\t" \
        "global_load_dwordx4 %4, %17, %18 sc0 sc1\n\t" \
        "global_load_dwordx4 %5, %17, %18 offset:64 sc0 sc1\n\t" \
        "global_load_dwordx4 %6, %17, %18 offset:128 sc0 sc1\n\t" \
        "global_load_dwordx4 %7, %17, %18 offset:192 sc0 sc1\n\t" \
        "global_load_dwordx4 %8, %17, %18 offset:256 sc0 sc1\n\t" \
        "global_load_dwordx4 %9, %17, %18 offset:320 sc0 sc1\n\t" \
        "global_load_dwordx4 %10, %17, %18 offset:384 sc0 sc1\n\t" \
        "global_load_dwordx4 %11, %17, %18 offset:448 sc0 sc1\n\t" \
        "s_waitcnt vmcnt(0)" \
        : "=&v"(XPQ[0]), "=&v"(XPQ[1]), "=&v"(XPQ[2]), "=&v"(XPQ[3]), \
          "=&v"(AFP[0]), "=&v"(AFP[1]), "=&v"(AFP[2]), "=&v"(AFP[3]), \
          "=&v"(AFP[4]), "=&v"(AFP[5]), "=&v"(AFP[6]), "=&v"(AFP[7]) \
        : "v"(vxpr[0]), "v"(vxpr[1]), "v"(vxpr[2]), "v"(vxpr[3]), \
          "s"(XPBASE), "v"(VSLR), "s"(SLBASE))

#define RETRY8(AFP, VSLR, SLBASE) \
    asm volatile( \
        "global_load_dwordx4 %0, %8, %9 sc0 sc1\n\t" \
        "global_load_dwordx4 %1, %8, %9 offset:64 sc0 sc1\n\t" \
        "global_load_dwordx4 %2, %8, %9 offset:128 sc0 sc1\n\t" \
        "global_load_dwordx4 %3, %8, %9 offset:192 sc0 sc1\n\t" \
        "global_load_dwordx4 %4, %8, %9 offset:256 sc0 sc1\n\t" \
        "global_load_dwordx4 %5, %8, %9 offset:320 sc0 sc1\n\t" \
        "global_load_dwordx4 %6, %8, %9 offset:384 sc0 sc1\n\t" \
        "global_load_dwordx4 %7, %8, %9 offset:448 sc0 sc1\n\t" \
        "s_waitcnt vmcnt(0)" \
        : "=&v"(AFP[0]), "=&v"(AFP[1]), "=&v"(AFP[2]), "=&v"(AFP[3]), \
          "=&v"(AFP[4]), "=&v"(AFP[5]), "=&v"(AFP[6]), "=&v"(AFP[7]) \
        : "v"(VSLR), "s"(SLBASE))

#define SENT_CHECK(AFP, BAD) \
    { BAD = 0; \
      _Pragma("unroll") \
      for (int _i = 0; _i < 8; ++_i) \
          _Pragma("unroll") \
          for (int _j = 0; _j < 4; ++_j) \
              BAD |= (AFP[_i][_j] == SENT); }

// 16 slot stores (MALL sc0 sc1) + 16 out stores (HBM) -- fire and forget
#define STORE_SLOT_OUT(PK, VSLW, SLWB, OUTB) \
    asm volatile( \
        "global_store_dword %16, %0, %21 sc0 sc1\n\t" \
        "global_store_dword %16, %1, %21 offset:512 sc0 sc1\n\t" \
        "global_store_dword %16, %2, %21 offset:1024 sc0 sc1\n\t" \
        "global_store_dword %16, %3, %21 offset:1536 sc0 sc1\n\t" \
        "global_store_dword %16, %4, %21 offset:32 sc0 sc1\n\t" \
        "global_store_dword %16, %5, %21 offset:544 sc0 sc1\n\t" \
        "global_store_dword %16, %6, %21 offset:1056 sc0 sc1\n\t" \
        "global_store_dword %16, %7, %21 offset:1568 sc0 sc1\n\t" \
        "global_store_dword %16, %8, %21 offset:64 sc0 sc1\n\t" \
        "global_store_dword %16, %9, %21 offset:576 sc0 sc1\n\t" \
        "global_store_dword %16, %10, %21 offset:1088 sc0 sc1\n\t" \
        "global_store_dword %16, %11, %21 offset:1600 sc0 sc1\n\t" \
        "global_store_dword %16, %12, %21 offset:96 sc0 sc1\n\t" \
        "global_store_dword %16, %13, %21 offset:608 sc0 sc1\n\t" \
        "global_store_dword %16, %14, %21 offset:1120 sc0 sc1\n\t" \
        "global_store_dword %16, %15, %21 offset:1632 sc0 sc1\n\t" \
        "global_store_dword %17, %0, %22\n\t" \
        "global_store_dword %18, %1, %22\n\t" \
        "global_store_dword %19, %2, %22\n\t" \
        "global_store_dword %20, %3, %22\n\t" \
        "global_store_dword %17, %4, %22 offset:32\n\t" \
        "global_store_dword %18, %5, %22 offset:32\n\t" \
        "global_store_dword %19, %6, %22 offset:32\n\t" \
        "global_store_dword %20, %7, %22 offset:32\n\t" \
        "global_store_dword %17, %8, %22 offset:64\n\t" \
        "global_store_dword %18, %9, %22 offset:64\n\t" \
        "global_store_dword %19, %10, %22 offset:64\n\t" \
        "global_store_dword %20, %11, %22 offset:64\n\t" \
        "global_store_dword %17, %12, %22 offset:96\n\t" \
        "global_store_dword %18, %13, %22 offset:96\n\t" \
        "global_store_dword %19, %14, %22 offset:96\n\t" \
        "global_store_dword %20, %15, %22 offset:96" \
        :: "v"(PK[0]), "v"(PK[1]), "v"(PK[2]), "v"(PK[3]), \
           "v"(PK[4]), "v"(PK[5]), "v"(PK[6]), "v"(PK[7]), \
           "v"(PK[8]), "v"(PK[9]), "v"(PK[10]), "v"(PK[11]), \
           "v"(PK[12]), "v"(PK[13]), "v"(PK[14]), "v"(PK[15]), \
           "v"(VSLW), "v"(vout[0]), "v"(vout[1]), "v"(vout[2]), "v"(vout[3]), \
           "s"(SLWB), "s"(OUTB) \
        : "memory")

__global__ __launch_bounds__(256, 1) void recur_kernel(
    const float* __restrict__ xp,          // [B][T][H'] f32, H-permuted
    const unsigned short* __restrict__ w,  // [H][H] bf16
    unsigned short* __restrict__ out_bf,   // [B][T][H] bf16, standard layout
    float* __restrict__ h_final,           // [B][H] f32
    unsigned short* __restrict__ slots)    // [4 blk][4 slot][32][256] bf16, 0x7F-filled
{
    __shared__ __align__(16) unsigned short lds[32 * 280];   // rows 0-15=A, 16-31=B

    const int bid = blockIdx.x;            // 4 blocks
    const int g01 = bid >> 1;
    const int jw  = bid & 1;
    const int pjw = jw ^ 1;
    const int b0A = g01 * 32;
    const int b0B = g01 * 32 + 16;
    const int tid = threadIdx.x;
    const int wv  = tid >> 6;
    const int l   = tid & 63;
    const int lr  = l & 15;
    const int lk  = (l >> 4) * 8;
    const int jn0 = jw * 256 + wv * 64;
    const int erow_l = (l >> 4) * 4;

    // ---- per-group base pointers (SGPR) ----
    const float*          xpA  = xp     + (size_t)b0A * T_ * H_;
    const float*          xpB  = xp     + (size_t)b0B * T_ * H_;
    unsigned short*       outA = out_bf + (size_t)b0A * T_ * H_;
    unsigned short*       outB = out_bf + (size_t)b0B * T_ * H_;
    float*                hfA  = h_final + (size_t)b0A * H_;
    float*                hfB  = h_final + (size_t)b0B * H_;
    unsigned short*       slW  = slots + (size_t)bid * BLK_SLOT_ELEMS;
    const unsigned short* slRA = slots + (size_t)(bid ^ 1) * BLK_SLOT_ELEMS;
    const unsigned short* slRB = slRA + 4096;   // +8192 B = group-B rows

    // ---- weights -> registers, once (own k-half, peer k-half) ----
    bf16x8 bwo[4][8], bwp[4][8];
    #pragma unroll
    for (int nt = 0; nt < 4; ++nt) {
        unsigned int vo = (unsigned)((jn0 + nt * 16 + lr) * (H_ * 2) + jw  * 512 + lk * 2);
        unsigned int vp = (unsigned)((jn0 + nt * 16 + lr) * (H_ * 2) + pjw * 512 + lk * 2);
        LDW8(bwo[nt], vo);
        LDW8(bwp[nt], vp);
    }

    // ---- voffsets (group-local; group selected by SGPR base) ----
    unsigned int vxpr[4], vout[4];
    #pragma unroll
    for (int r = 0; r < 4; ++r) {
        // permuted xp: h' = lr*32 + jw*16 + wv*4 + nt  (nt contiguous)
        vxpr[r] = (unsigned)(((erow_l + r) * T_ * H_ + lr * 32 + jw * 16 + wv * 4) * 4);
        vout[r] = (unsigned)(((erow_l + r) * T_) * H_ * 2 + (jn0 + lr) * 2);
    }
    const unsigned int vslr0 = (unsigned)(lr * 512 + lk * 2);            // peer A-frag voffset
    const unsigned int vslw0 = (unsigned)(erow_l * 512 + (wv * 64 + lr) * 2);
    const unsigned int vsent0 = (unsigned)(tid * 64);
    const u32x4 sentq = {SENT, SENT, SENT, SENT};
    const int cb = wv * 32 + (lr >> 1);

    // ================= t = 0 peel: h1 = tanh(xp[0]) for both groups =================
    #pragma unroll
    for (int grp = 0; grp < 2; ++grp) {
        const float* xpg = grp ? xpB : xpA;
        unsigned short* outg = grp ? outB : outA;
        f32x4 xpq[4];
        asm volatile(
            "global_load_dwordx4 %0, %4, %8\n\t"
            "global_load_dwordx4 %1, %5, %8\n\t"
            "global_load_dwordx4 %2, %6, %8\n\t"
            "global_load_dwordx4 %3, %7, %8\n\t"
            "s_waitcnt vmcnt(0)"
            : "=&v"(xpq[0]), "=&v"(xpq[1]), "=&v"(xpq[2]), "=&v"(xpq[3])
            : "v"(vxpr[0]), "v"(vxpr[1]), "v"(vxpr[2]), "v"(vxpr[3]), "s"(xpg));
        unsigned int pk[16];
        #pragma unroll
        for (int nt = 0; nt < 4; ++nt)
            #pragma unroll
            for (int r = 0; r < 4; ++r) {
                float hv = tanh_fast(xpq[r][nt]);
                unsigned int mine = f2bf(hv);
                unsigned int oth = (unsigned int)__shfl_xor((int)mine, 1, 64);
                pk[nt * 4 + r] = mine | (oth << 16);
            }
        if (!(lr & 1)) {
            unsigned int* lw = (unsigned int*)lds;
            #pragma unroll
            for (int nt = 0; nt < 4; ++nt)
                #pragma unroll
                for (int r = 0; r < 4; ++r)
                    lw[(grp * 16 + erow_l + r) * 140 + cb + nt * 8] = pk[nt * 4 + r];
            unsigned int vslw = vslw0 + 1u * SLOT_BYTES + (unsigned)(grp * 8192);
            STORE_SLOT_OUT(pk, vslw, slW, outg);
        }
    }
    __syncthreads();
    #pragma unroll
    for (int r = 0; r < 4; ++r) { vxpr[r] += H_ * 4; vout[r] += H_ * 2; }

    // ================= main loop t = 1..T-1 =================
    for (int t = 1; t < T_; ++t) {
        // own-half MFMA, group A then B (covers peer store visibility window)
        f32x4 accA[4] = {{0,0,0,0},{0,0,0,0},{0,0,0,0},{0,0,0,0}};
        f32x4 accB[4] = {{0,0,0,0},{0,0,0,0},{0,0,0,0},{0,0,0,0}};
        {
            bf16x8 afo[8];
            const unsigned short* lrb = lds + lr * 280 + lk;
            #pragma unroll
            for (int i = 0; i < 8; ++i) afo[i] = *reinterpret_cast<const bf16x8*>(lrb + i * 32);
            #pragma unroll
            for (int i = 0; i < 8; ++i) {
                accA[0] = __builtin_amdgcn_mfma_f32_16x16x32_bf16(afo[i], bwo[0][i], accA[0], 0, 0, 0);
                accA[1] = __builtin_amdgcn_mfma_f32_16x16x32_bf16(afo[i], bwo[1][i], accA[1], 0, 0, 0);
                accA[2] = __builtin_amdgcn_mfma_f32_16x16x32_bf16(afo[i], bwo[2][i], accA[2], 0, 0, 0);
                accA[3] = __builtin_amdgcn_mfma_f32_16x16x32_bf16(afo[i], bwo[3][i], accA[3], 0, 0, 0);
            }
        }
        {
            bf16x8 afo[8];
            const unsigned short* lrb = lds + (16 + lr) * 280 + lk;
            #pragma unroll
            for (int i = 0; i < 8; ++i) afo[i] = *reinterpret_cast<const bf16x8*>(lrb + i * 32);
            #pragma unroll
            for (int i = 0; i < 8; ++i) {
                accB[0] = __builtin_amdgcn_mfma_f32_16x16x32_bf16(afo[i], bwo[0][i], accB[0], 0, 0, 0);
                accB[1] = __builtin_amdgcn_mfma_f32_16x16x32_bf16(afo[i], bwo[1][i], accB[1], 0, 0, 0);
                accB[2] = __builtin_amdgcn_mfma_f32_16x16x32_bf16(afo[i], bwo[2][i], accB[2], 0, 0, 0);
                accB[3] = __builtin_amdgcn_mfma_f32_16x16x32_bf16(afo[i], bwo[3][i], accB[3], 0, 0, 0);
            }
        }
        __builtin_amdgcn_sched_barrier(0);

        const unsigned int vslr = vslr0 + (unsigned)(t & 3) * SLOT_BYTES;

        // group A: load xp + poll peer, then peer-half MFMA
        f32x4 xpqA[4];
        u32x4 afpA[8];
        LOAD_XP_PEER(xpqA, afpA, vslr, xpA, slRA);
        int bad;
        SENT_CHECK(afpA, bad);
        while (__any(bad)) { RETRY8(afpA, vslr, slRA); SENT_CHECK(afpA, bad); }
        __builtin_amdgcn_sched_barrier(0);
        #pragma unroll
        for (int i = 0; i < 8; ++i) {
            bf16x8 a = __builtin_bit_cast(bf16x8, afpA[i]);
            accA[0] = __builtin_amdgcn_mfma_f32_16x16x32_bf16(a, bwp[0][i], accA[0], 0, 0, 0);
            accA[1] = __builtin_amdgcn_mfma_f32_16x16x32_bf16(a, bwp[1][i], accA[1], 0, 0, 0);
            accA[2] = __builtin_amdgcn_mfma_f32_16x16x32_bf16(a, bwp[2][i], accA[2], 0, 0, 0);
            accA[3] = __builtin_amdgcn_mfma_f32_16x16x32_bf16(a, bwp[3][i], accA[3], 0, 0, 0);
        }

        // group B: load xp + poll peer, then peer-half MFMA
        f32x4 xpqB[4];
        u32x4 afpB[8];
        LOAD_XP_PEER(xpqB, afpB, vslr, xpB, slRB);
        SENT_CHECK(afpB, bad);
        while (__any(bad)) { RETRY8(afpB, vslr, slRB); SENT_CHECK(afpB, bad); }
        __builtin_amdgcn_sched_barrier(0);
        #pragma unroll
        for (int i = 0; i < 8; ++i) {
            bf16x8 a = __builtin_bit_cast(bf16x8, afpB[i]);
            accB[0] = __builtin_amdgcn_mfma_f32_16x16x32_bf16(a, bwp[0][i], accB[0], 0, 0, 0);
            accB[1] = __builtin_amdgcn_mfma_f32_16x16x32_bf16(a, bwp[1][i], accB[1], 0, 0, 0);
            accB[2] = __builtin_amdgcn_mfma_f32_16x16x32_bf16(a, bwp[2][i], accB[2], 0, 0, 0);
            accB[3] = __builtin_amdgcn_mfma_f32_16x16x32_bf16(a, bwp[3][i], accB[3], 0, 0, 0);
        }

        // epilogues
        #pragma unroll
        for (int grp = 0; grp < 2; ++grp) {
            f32x4* acc = grp ? accB : accA;
            f32x4* xpq = grp ? xpqB : xpqA;
            float* hfg = grp ? hfB : hfA;
            unsigned short* outg = grp ? outB : outA;
            unsigned int pk[16];
            #pragma unroll
            for (int nt = 0; nt < 4; ++nt)
                #pragma unroll
                for (int r = 0; r < 4; ++r) {
                    float pre = acc[nt][r] + xpq[r][nt];
                    float hv = tanh_fast(pre);
                    if (t == T_ - 1)
                        hfg[(size_t)(erow_l + r) * H_ + jn0 + nt * 16 + lr] = hv;
                    unsigned int mine = f2bf(hv);
                    unsigned int oth = (unsigned int)__shfl_xor((int)mine, 1, 64);
                    pk[nt * 4 + r] = mine | (oth << 16);
                }
            if (!(lr & 1)) {
                unsigned int* lw = (unsigned int*)lds;
                #pragma unroll
                for (int nt = 0; nt < 4; ++nt)
                    #pragma unroll
                    for (int r = 0; r < 4; ++r)
                        lw[(grp * 16 + erow_l + r) * 140 + cb + nt * 8] = pk[nt * 4 + r];
                unsigned int vslw = vslw0 + (unsigned)((t + 1) & 3) * SLOT_BYTES + (unsigned)(grp * 8192);
                STORE_SLOT_OUT(pk, vslw, slW, outg);
            }
        }

        __syncthreads();

        // re-sentinel consumed slot in the peer's region (whole 16 KB, fire-and-forget)
        {
            unsigned int vs = vsent0 + (unsigned)(t & 3) * SLOT_BYTES;
            asm volatile(
                "global_store_dwordx4 %0, %1, %2 sc0 sc1\n\t"
                "global_store_dwordx4 %0, %1, %2 offset:16 sc0 sc1\n\t"
                "global_store_dwordx4 %0, %1, %2 offset:32 sc0 sc1\n\t"
                "global_store_dwordx4 %0, %1, %2 offset:48 sc0 sc1"
                :: "v"(vs), "v"(sentq), "s"(slRA) : "memory");
        }
        #pragma unroll
        for (int r = 0; r < 4; ++r) { vxpr[r] += H_ * 4; vout[r] += H_ * 2; }
    }
}

// ---------------- workspace layout (bytes) ----------------
#define OFF_XBF    ((size_t)0)
#define OFF_WIH0   ((size_t)16777216)
#define OFF_WHH0   ((size_t)17039360)
#define OFF_WIH1   ((size_t)17563648)
#define OFF_WHH1   ((size_t)18087936)
#define OFF_FCW    ((size_t)18612224)
#define OFF_XP     ((size_t)18874368)
#define OFF_OUTBF  ((size_t)85983232)
#define OFF_SLOTS  ((size_t)119537664)   // 4 blocks x 4 slots x 16384 B = 262144
#define WS_NEED    ((size_t)119799808)

extern "C" void kernel_launch(void* const* d_in, const int* in_sizes, int n_in,
                              void* d_out, int out_size, void* d_ws, size_t ws_size,
                              hipStream_t stream) {
    if (ws_size < WS_NEED) return;
    const float* x     = (const float*)d_in[0];
    const float* w_ih0 = (const float*)d_in[1];
    const float* w_hh0 = (const float*)d_in[2];
    const float* b_ih0 = (const float*)d_in[3];
    const float* b_hh0 = (const float*)d_in[4];
    const float* w_ih1 = (const float*)d_in[5];
    const float* w_hh1 = (const float*)d_in[6];
    const float* b_ih1 = (const float*)d_in[7];
    const float* b_hh1 = (const float*)d_in[8];
    const float* fc_w  = (const float*)d_in[9];
    const float* fc_b  = (const float*)d_in[10];

    char* ws = (char*)d_ws;
    unsigned short* x_bf     = (unsigned short*)(ws + OFF_XBF);
    unsigned short* w_ih0_bf = (unsigned short*)(ws + OFF_WIH0);
    unsigned short* w_hh0_bf = (unsigned short*)(ws + OFF_WHH0);
    unsigned short* w_ih1_bf = (unsigned short*)(ws + OFF_WIH1);
    unsigned short* w_hh1_bf = (unsigned short*)(ws + OFF_WHH1);
    unsigned short* fc_w_bf  = (unsigned short*)(ws + OFF_FCW);
    float*          xp       = (float*)(ws + OFF_XP);
    unsigned short* out_bf   = (unsigned short*)(ws + OFF_OUTBF);
    unsigned short* slots    = (unsigned short*)(ws + OFF_SLOTS);

    float* out  = (float*)d_out;
    float* hid0 = out + (size_t)B_ * T_ * O_;
    float* hid1 = hid0 + (size_t)B_ * H_;

    hipMemsetAsync(ws + OFF_SLOTS, 0x7F, 262144, stream);

    auto cvt = [&](const float* in, unsigned short* o, int n) {
        int n4 = n / 4;
        cvt_kernel<<<(n4 + 255) / 256, 256, 0, stream>>>(in, o, n4);
    };
    cvt(x,     x_bf,     B_ * T_ * I_);
    cvt(w_ih0, w_ih0_bf, H_ * I_);
    cvt(w_hh0, w_hh0_bf, H_ * H_);
    cvt(w_ih1, w_ih1_bf, H_ * H_);
    cvt(w_hh1, w_hh1_bf, H_ * H_);
    cvt(fc_w,  fc_w_bf,  O_ * H_);

    const int M = B_ * T_;

    // xp0 = x @ w_ih0^T + biases, H-permuted store
    gemm_kernel<<<dim3(M / 64, H_ / 64), 256, 0, stream>>>(
        x_bf, w_ih0_bf, b_ih0, b_hh0, xp, M, H_, I_, 1);

    recur_kernel<<<4, 256, 0, stream>>>(xp, w_hh0_bf, out_bf, hid0, slots);

    // xp1 = out0 @ w_ih1^T + biases, H-permuted store
    gemm_kernel<<<dim3(M / 64, H_ / 64), 256, 0, stream>>>(
        out_bf, w_ih1_bf, b_ih1, b_hh1, xp, M, H_, H_, 1);

    hipMemsetAsync(ws + OFF_SLOTS, 0x7F, 262144, stream);

    recur_kernel<<<4, 256, 0, stream>>>(xp, w_hh1_bf, out_bf, hid1, slots);

    // out = out1 @ fc_w^T + fc_b (standard layout)
    gemm_kernel<<<dim3(M / 64, O_ / 64), 256, 0, stream>>>(
        out_bf, fc_w_bf, fc_b, nullptr, out, M, O_, H_, 0);
}

// Round 9
// 4242.985 us; speedup vs baseline: 1.6336x; 1.6336x over previous
//
#include <hip/hip_runtime.h>

#define B_  64
#define T_  512
#define I_  256
#define H_  512
#define O_  256
#define SENT 0x7F7F7F7Fu

typedef __attribute__((ext_vector_type(8))) __bf16 bf16x8;
typedef __attribute__((ext_vector_type(4))) float f32x4;
typedef unsigned int u32x4 __attribute__((ext_vector_type(4)));

__device__ __forceinline__ unsigned short f2bf(float f) {
    unsigned int u = __float_as_uint(f);
    unsigned int r = (u + 0x7fffu + ((u >> 16) & 1u)) >> 16;
    return (unsigned short)r;
}

__device__ __forceinline__ float tanh_fast(float x) {
    float e = __expf(2.0f * x);
    float d = e + 1.0f;
    float r;
    asm("v_rcp_f32 %0, %1" : "=v"(r) : "v"(d));
    return 1.0f - 2.0f * r;
}

// ---------------- convert f32 -> bf16 ----------------
__global__ void cvt_kernel(const float* __restrict__ in, unsigned short* __restrict__ out, int n4) {
    int i = blockIdx.x * blockDim.x + threadIdx.x;
    if (i >= n4) return;
    float4 f = reinterpret_cast<const float4*>(in)[i];
    ushort4 o;
    o.x = f2bf(f.x); o.y = f2bf(f.y); o.z = f2bf(f.z); o.w = f2bf(f.w);
    reinterpret_cast<ushort4*>(out)[i] = o;
}

// ---------------- generic GEMM: C = A @ Bw^T + b0 + b1 ----------------
// perm: store C with col' = (col&15)*32 + (col>>4)  (N==512 only)
// histA: A is hist layout [4][512][16][512] bf16 (m = b*512+t; b = g*16+r)
__global__ __launch_bounds__(256) void gemm_kernel(
    const unsigned short* __restrict__ A,
    const unsigned short* __restrict__ Bw,
    const float* __restrict__ b0,
    const float* __restrict__ b1,
    float* __restrict__ C,
    int M, int N, int K, int perm, int histA)
{
    const int m0 = blockIdx.x * 64;
    const int n0 = blockIdx.y * 64;
    const int tid = threadIdx.x;
    const int wv = tid >> 6;
    const int l = tid & 63;
    const int lr = l & 15;
    const int lk = (l >> 4) * 8;
    const int arow = m0 + wv * 16 + lr;

    size_t abase;
    if (histA) {
        int b = arow >> 9, t = arow & 511;
        int g = b >> 4, r = b & 15;
        abase = ((size_t)(g * 512 + t) * 16 + r) * 512;
    } else {
        abase = (size_t)arow * K;
    }

    f32x4 acc[4] = {{0,0,0,0},{0,0,0,0},{0,0,0,0},{0,0,0,0}};
    const int nks = K / 32;
    for (int ks = 0; ks < nks; ++ks) {
        bf16x8 a = *reinterpret_cast<const bf16x8*>(A + abase + ks * 32 + lk);
        #pragma unroll
        for (int nt = 0; nt < 4; ++nt) {
            bf16x8 b = *reinterpret_cast<const bf16x8*>(Bw + (size_t)(n0 + nt * 16 + lr) * K + ks * 32 + lk);
            acc[nt] = __builtin_amdgcn_mfma_f32_16x16x32_bf16(a, b, acc[nt], 0, 0, 0);
        }
    }
    #pragma unroll
    for (int nt = 0; nt < 4; ++nt) {
        #pragma unroll
        for (int r = 0; r < 4; ++r) {
            int row = m0 + wv * 16 + (l >> 4) * 4 + r;
            int col = n0 + nt * 16 + lr;
            float v = acc[nt][r];
            if (b0) v += b0[col];
            if (b1) v += b1[col];
            int cs = perm ? ((col & 15) * 32 + (col >> 4)) : col;
            C[(size_t)row * N + cs] = v;
        }
    }
}

// ---------------- recurrence (T-deep hist, data-as-flag, no resets) ----------------
#define LDW8(ARR, BASE) \
    asm volatile( \
        "global_load_dwordx4 %0, %8, %9 offset:0\n\t" \
        "global_load_dwordx4 %1, %8, %9 offset:64\n\t" \
        "global_load_dwordx4 %2, %8, %9 offset:128\n\t" \
        "global_load_dwordx4 %3, %8, %9 offset:192\n\t" \
        "global_load_dwordx4 %4, %8, %9 offset:256\n\t" \
        "global_load_dwordx4 %5, %8, %9 offset:320\n\t" \
        "global_load_dwordx4 %6, %8, %9 offset:384\n\t" \
        "global_load_dwordx4 %7, %8, %9 offset:448\n\t" \
        "s_waitcnt vmcnt(0)" \
        : "=&v"(ARR[0]), "=&v"(ARR[1]), "=&v"(ARR[2]), "=&v"(ARR[3]), \
          "=&v"(ARR[4]), "=&v"(ARR[5]), "=&v"(ARR[6]), "=&v"(ARR[7]) \
        : "v"(BASE), "s"(w))

// 4 permuted-xp dwordx4 (HBM) + 8 peer-h dwordx4 (MALL), one wait
#define LOAD_XP_PEER(XPQ, AFP, VSLR) \
    asm volatile( \
        "global_load_dwordx4 %0, %12, %16\n\t" \
        "global_load_dwordx4 %1, %13, %16\n\t" \
        "global_load_dwordx4 %2, %14, %16\n\t" \
        "global_load_dwordx4 %3, %15, %16\n\t" \
        "global_load_dwordx4 %4, %17, %18 sc0 sc1\n\t" \
        "global_load_dwordx4 %5, %17, %18 offset:64 sc0 sc1\n\t" \
        "global_load_dwordx4 %6, %17, %18 offset:128 sc0 sc1\n\t" \
        "global_load_dwordx4 %7, %17, %18 offset:192 sc0 sc1\n\t" \
        "global_load_dwordx4 %8, %17, %18 offset:256 sc0 sc1\n\t" \
        "global_load_dwordx4 %9, %17, %18 offset:320 sc0 sc1\n\t" \
        "global_load_dwordx4 %10, %17, %18 offset:384 sc0 sc1\n\t" \
        "global_load_dwordx4 %11, %17, %18 offset:448 sc0 sc1\n\t" \
        "s_waitcnt vmcnt(0)" \
        : "=&v"(XPQ[0]), "=&v"(XPQ[1]), "=&v"(XPQ[2]), "=&v"(XPQ[3]), \
          "=&v"(AFP[0]), "=&v"(AFP[1]), "=&v"(AFP[2]), "=&v"(AFP[3]), \
          "=&v"(AFP[4]), "=&v"(AFP[5]), "=&v"(AFP[6]), "=&v"(AFP[7]) \
        : "v"(vxpr[0]), "v"(vxpr[1]), "v"(vxpr[2]), "v"(vxpr[3]), \
          "s"(xpg), "v"(VSLR), "s"(histg))

#define RETRY8(AFP, VSLR) \
    asm volatile( \
        "global_load_dwordx4 %0, %8, %9 sc0 sc1\n\t" \
        "global_load_dwordx4 %1, %8, %9 offset:64 sc0 sc1\n\t" \
        "global_load_dwordx4 %2, %8, %9 offset:128 sc0 sc1\n\t" \
        "global_load_dwordx4 %3, %8, %9 offset:192 sc0 sc1\n\t" \
        "global_load_dwordx4 %4, %8, %9 offset:256 sc0 sc1\n\t" \
        "global_load_dwordx4 %5, %8, %9 offset:320 sc0 sc1\n\t" \
        "global_load_dwordx4 %6, %8, %9 offset:384 sc0 sc1\n\t" \
        "global_load_dwordx4 %7, %8, %9 offset:448 sc0 sc1\n\t" \
        "s_waitcnt vmcnt(0)" \
        : "=&v"(AFP[0]), "=&v"(AFP[1]), "=&v"(AFP[2]), "=&v"(AFP[3]), \
          "=&v"(AFP[4]), "=&v"(AFP[5]), "=&v"(AFP[6]), "=&v"(AFP[7]) \
        : "v"(VSLR), "s"(histg))

#define SENT_CHECK(AFP, BAD) \
    { BAD = 0; \
      _Pragma("unroll") \
      for (int _i = 0; _i < 8; ++_i) \
          _Pragma("unroll") \
          for (int _j = 0; _j < 4; ++_j) \
              BAD |= (AFP[_i][_j] == SENT); }

// 16 hist stores (MALL sc0 sc1) -- fire and forget (this IS the output write)
#define STORE16(PK, VHW) \
    asm volatile( \
        "global_store_dword %16, %0, %17 sc0 sc1\n\t" \
        "global_store_dword %16, %1, %17 offset:1024 sc0 sc1\n\t" \
        "global_store_dword %16, %2, %17 offset:2048 sc0 sc1\n\t" \
        "global_store_dword %16, %3, %17 offset:3072 sc0 sc1\n\t" \
        "global_store_dword %16, %4, %17 offset:32 sc0 sc1\n\t" \
        "global_store_dword %16, %5, %17 offset:1056 sc0 sc1\n\t" \
        "global_store_dword %16, %6, %17 offset:2080 sc0 sc1\n\t" \
        "global_store_dword %16, %7, %17 offset:3104 sc0 sc1\n\t" \
        "global_store_dword %16, %8, %17 offset:64 sc0 sc1\n\t" \
        "global_store_dword %16, %9, %17 offset:1088 sc0 sc1\n\t" \
        "global_store_dword %16, %10, %17 offset:2112 sc0 sc1\n\t" \
        "global_store_dword %16, %11, %17 offset:3136 sc0 sc1\n\t" \
        "global_store_dword %16, %12, %17 offset:96 sc0 sc1\n\t" \
        "global_store_dword %16, %13, %17 offset:1120 sc0 sc1\n\t" \
        "global_store_dword %16, %14, %17 offset:2144 sc0 sc1\n\t" \
        "global_store_dword %16, %15, %17 offset:3168 sc0 sc1" \
        :: "v"(PK[0]), "v"(PK[1]), "v"(PK[2]), "v"(PK[3]), \
           "v"(PK[4]), "v"(PK[5]), "v"(PK[6]), "v"(PK[7]), \
           "v"(PK[8]), "v"(PK[9]), "v"(PK[10]), "v"(PK[11]), \
           "v"(PK[12]), "v"(PK[13]), "v"(PK[14]), "v"(PK[15]), \
           "v"(VHW), "s"(histg) \
        : "memory")

__global__ __launch_bounds__(256, 1) void recur_kernel(
    const float* __restrict__ xp,          // [B][T][H'] f32, H-permuted
    const unsigned short* __restrict__ w,  // [H][H] bf16
    unsigned short* __restrict__ hist,     // [4][T][16][512] bf16, 0x7F pre-filled
    float* __restrict__ h_final)           // [B][H] f32
{
    __shared__ __align__(16) unsigned short lds[16 * 280];   // own-half h staging

    const int bid = blockIdx.x;            // 8 blocks
    const int g   = bid >> 1;
    const int jw  = bid & 1;
    const int pjw = jw ^ 1;
    const int b0  = g * 16;
    const int tid = threadIdx.x;
    const int wv  = tid >> 6;
    const int l   = tid & 63;
    const int lr  = l & 15;
    const int lk  = (l >> 4) * 8;
    const int jn0 = jw * 256 + wv * 64;
    const int erow_l = (l >> 4) * 4;

    const float*    xpg   = xp + (size_t)b0 * T_ * H_;
    unsigned short* histg = hist + (size_t)g * T_ * 16 * 512;
    float*          hfg   = h_final + (size_t)b0 * H_;

    // ---- weights -> registers, once (own k-half, peer k-half) ----
    bf16x8 bwo[4][8], bwp[4][8];
    #pragma unroll
    for (int nt = 0; nt < 4; ++nt) {
        unsigned int vo = (unsigned)((jn0 + nt * 16 + lr) * (H_ * 2) + jw  * 512 + lk * 2);
        unsigned int vp = (unsigned)((jn0 + nt * 16 + lr) * (H_ * 2) + pjw * 512 + lk * 2);
        LDW8(bwo[nt], vo);
        LDW8(bwp[nt], vp);
    }

    // ---- voffsets ----
    unsigned int vxpr[4];
    #pragma unroll
    for (int r = 0; r < 4; ++r)
        vxpr[r] = (unsigned)(((erow_l + r) * T_ * H_ + lr * 32 + jw * 16 + wv * 4) * 4);
    const unsigned int vslr0 = (unsigned)(lr * 1024 + pjw * 512 + lk * 2);
    const unsigned int vhw0  = (unsigned)(erow_l * 1024 + (jn0 + lr) * 2);
    const int cb = wv * 32 + (lr >> 1);

    // ================= t = 0 peel: hist[0] = tanh(xp[0]) =================
    {
        f32x4 xpq[4];
        asm volatile(
            "global_load_dwordx4 %0, %4, %8\n\t"
            "global_load_dwordx4 %1, %5, %8\n\t"
            "global_load_dwordx4 %2, %6, %8\n\t"
            "global_load_dwordx4 %3, %7, %8\n\t"
            "s_waitcnt vmcnt(0)"
            : "=&v"(xpq[0]), "=&v"(xpq[1]), "=&v"(xpq[2]), "=&v"(xpq[3])
            : "v"(vxpr[0]), "v"(vxpr[1]), "v"(vxpr[2]), "v"(vxpr[3]), "s"(xpg));
        unsigned int pk[16];
        #pragma unroll
        for (int nt = 0; nt < 4; ++nt)
            #pragma unroll
            for (int r = 0; r < 4; ++r) {
                float hv = tanh_fast(xpq[r][nt]);
                unsigned int mine = f2bf(hv);
                unsigned int oth = (unsigned int)__shfl_xor((int)mine, 1, 64);
                pk[nt * 4 + r] = mine | (oth << 16);
            }
        if (!(lr & 1)) {
            unsigned int* lw = (unsigned int*)lds;
            #pragma unroll
            for (int nt = 0; nt < 4; ++nt)
                #pragma unroll
                for (int r = 0; r < 4; ++r)
                    lw[(erow_l + r) * 140 + cb + nt * 8] = pk[nt * 4 + r];
            STORE16(pk, vhw0);
        }
        __syncthreads();
        #pragma unroll
        for (int r = 0; r < 4; ++r) vxpr[r] += H_ * 4;
    }

    // ================= main loop t = 1..T-1 =================
    for (int t = 1; t < T_; ++t) {
        // A: own-half MFMA from LDS (h_{t-1} own cols)
        f32x4 acc[4] = {{0,0,0,0},{0,0,0,0},{0,0,0,0},{0,0,0,0}};
        {
            bf16x8 afo[8];
            const unsigned short* lrb = lds + lr * 280 + lk;
            #pragma unroll
            for (int i = 0; i < 8; ++i)
                afo[i] = *reinterpret_cast<const bf16x8*>(lrb + i * 32);
            #pragma unroll
            for (int i = 0; i < 8; ++i) {
                acc[0] = __builtin_amdgcn_mfma_f32_16x16x32_bf16(afo[i], bwo[0][i], acc[0], 0, 0, 0);
                acc[1] = __builtin_amdgcn_mfma_f32_16x16x32_bf16(afo[i], bwo[1][i], acc[1], 0, 0, 0);
                acc[2] = __builtin_amdgcn_mfma_f32_16x16x32_bf16(afo[i], bwo[2][i], acc[2], 0, 0, 0);
                acc[3] = __builtin_amdgcn_mfma_f32_16x16x32_bf16(afo[i], bwo[3][i], acc[3], 0, 0, 0);
            }
        }
        // all waves done READING lds before any wave's epilogue WRITES it
        __syncthreads();

        // B: xp loads + peer-half poll of hist[t-1] (data-as-flag)
        const unsigned int vslr = vslr0 + (unsigned)(t - 1) * 16384u;
        f32x4 xpq[4];
        u32x4 afp[8];
        LOAD_XP_PEER(xpq, afp, vslr);
        int bad;
        SENT_CHECK(afp, bad);
        while (__any(bad)) { RETRY8(afp, vslr); SENT_CHECK(afp, bad); }
        __builtin_amdgcn_sched_barrier(0);

        // C: peer-half MFMA
        #pragma unroll
        for (int i = 0; i < 8; ++i) {
            bf16x8 a = __builtin_bit_cast(bf16x8, afp[i]);
            acc[0] = __builtin_amdgcn_mfma_f32_16x16x32_bf16(a, bwp[0][i], acc[0], 0, 0, 0);
            acc[1] = __builtin_amdgcn_mfma_f32_16x16x32_bf16(a, bwp[1][i], acc[1], 0, 0, 0);
            acc[2] = __builtin_amdgcn_mfma_f32_16x16x32_bf16(a, bwp[2][i], acc[2], 0, 0, 0);
            acc[3] = __builtin_amdgcn_mfma_f32_16x16x32_bf16(a, bwp[3][i], acc[3], 0, 0, 0);
        }

        // D: epilogue -> hist[t] (LDS own staging + 16 sc0sc1 stores, no wait)
        unsigned int pk[16];
        #pragma unroll
        for (int nt = 0; nt < 4; ++nt)
            #pragma unroll
            for (int r = 0; r < 4; ++r) {
                float pre = acc[nt][r] + xpq[r][nt];
                float hv = tanh_fast(pre);
                if (t == T_ - 1)
                    hfg[(size_t)(erow_l + r) * H_ + jn0 + nt * 16 + lr] = hv;
                unsigned int mine = f2bf(hv);
                unsigned int oth = (unsigned int)__shfl_xor((int)mine, 1, 64);
                pk[nt * 4 + r] = mine | (oth << 16);
            }
        if (!(lr & 1)) {
            unsigned int* lw = (unsigned int*)lds;
            #pragma unroll
            for (int nt = 0; nt < 4; ++nt)
                #pragma unroll
                for (int r = 0; r < 4; ++r)
                    lw[(erow_l + r) * 140 + cb + nt * 8] = pk[nt * 4 + r];
            unsigned int vhw = vhw0 + (unsigned)t * 16384u;
            STORE16(pk, vhw);
        }

        // E: step barrier (LDS h_t visible for next own-half MFMA)
        __syncthreads();
        #pragma unroll
        for (int r = 0; r < 4; ++r) vxpr[r] += H_ * 4;
    }
}

// ---------------- workspace layout (bytes) ----------------
#define OFF_XBF    ((size_t)0)
#define OFF_WIH0   ((size_t)16777216)
#define OFF_WHH0   ((size_t)17039360)
#define OFF_WIH1   ((size_t)17563648)
#define OFF_WHH1   ((size_t)18087936)
#define OFF_FCW    ((size_t)18612224)
#define OFF_XP     ((size_t)18874368)
#define OFF_HIST   ((size_t)85983232)    // 4 groups x 512 t x 16 x 512 bf16 = 33554432
#define WS_NEED    ((size_t)119799808)

extern "C" void kernel_launch(void* const* d_in, const int* in_sizes, int n_in,
                              void* d_out, int out_size, void* d_ws, size_t ws_size,
                              hipStream_t stream) {
    if (ws_size < WS_NEED) return;
    const float* x     = (const float*)d_in[0];
    const float* w_ih0 = (const float*)d_in[1];
    const float* w_hh0 = (const float*)d_in[2];
    const float* b_ih0 = (const float*)d_in[3];
    const float* b_hh0 = (const float*)d_in[4];
    const float* w_ih1 = (const float*)d_in[5];
    const float* w_hh1 = (const float*)d_in[6];
    const float* b_ih1 = (const float*)d_in[7];
    const float* b_hh1 = (const float*)d_in[8];
    const float* fc_w  = (const float*)d_in[9];
    const float* fc_b  = (const float*)d_in[10];

    char* ws = (char*)d_ws;
    unsigned short* x_bf     = (unsigned short*)(ws + OFF_XBF);
    unsigned short* w_ih0_bf = (unsigned short*)(ws + OFF_WIH0);
    unsigned short* w_hh0_bf = (unsigned short*)(ws + OFF_WHH0);
    unsigned short* w_ih1_bf = (unsigned short*)(ws + OFF_WIH1);
    unsigned short* w_hh1_bf = (unsigned short*)(ws + OFF_WHH1);
    unsigned short* fc_w_bf  = (unsigned short*)(ws + OFF_FCW);
    float*          xp       = (float*)(ws + OFF_XP);
    unsigned short* hist     = (unsigned short*)(ws + OFF_HIST);

    float* out  = (float*)d_out;
    float* hid0 = out + (size_t)B_ * T_ * O_;
    float* hid1 = hid0 + (size_t)B_ * H_;

    auto cvt = [&](const float* in, unsigned short* o, int n) {
        int n4 = n / 4;
        cvt_kernel<<<(n4 + 255) / 256, 256, 0, stream>>>(in, o, n4);
    };
    cvt(x,     x_bf,     B_ * T_ * I_);
    cvt(w_ih0, w_ih0_bf, H_ * I_);
    cvt(w_hh0, w_hh0_bf, H_ * H_);
    cvt(w_ih1, w_ih1_bf, H_ * H_);
    cvt(w_hh1, w_hh1_bf, H_ * H_);
    cvt(fc_w,  fc_w_bf,  O_ * H_);

    const int M = B_ * T_;

    // xp0 = x @ w_ih0^T + biases  (H-permuted store)
    gemm_kernel<<<dim3(M / 64, H_ / 64), 256, 0, stream>>>(
        x_bf, w_ih0_bf, b_ih0, b_hh0, xp, M, H_, I_, 1, 0);

    // sentinel-fill hist, then layer-0 recurrence writes hist = out0
    hipMemsetAsync(ws + OFF_HIST, 0x7F, 33554432, stream);
    recur_kernel<<<8, 256, 0, stream>>>(xp, w_hh0_bf, hist, hid0);

    // xp1 = out0 @ w_ih1^T + biases  (hist-layout A, H-permuted store)
    gemm_kernel<<<dim3(M / 64, H_ / 64), 256, 0, stream>>>(
        hist, w_ih1_bf, b_ih1, b_hh1, xp, M, H_, H_, 1, 1);

    // re-sentinel hist, then layer-1 recurrence writes hist = out1
    hipMemsetAsync(ws + OFF_HIST, 0x7F, 33554432, stream);
    recur_kernel<<<8, 256, 0, stream>>>(xp, w_hh1_bf, hist, hid1);

    // out = out1 @ fc_w^T + fc_b  (hist-layout A, standard store)
    gemm_kernel<<<dim3(M / 64, O_ / 64), 256, 0, stream>>>(
        hist, fc_w_bf, fc_b, nullptr, out, M, O_, H_, 0, 1);
}